// Round 8
// baseline (681.232 us; speedup 1.0000x reference)
//
#include <hip/hip_runtime.h>
#include <hip/hip_bf16.h>

typedef __bf16 bf16x8 __attribute__((ext_vector_type(8)));
typedef __bf16 bf16x4 __attribute__((ext_vector_type(4)));
typedef float f32x4 __attribute__((ext_vector_type(4)));

#define ROWSG 32768          // B*T
#define HPAD 72              // bf16 row stride
#define NN_OFF ((size_t)ROWSG)
#define EYE_OFF ((size_t)ROWSG + (size_t)ROWSG*64)

// weight-cache offsets (bf16 elements), all WT[n][k] row-major, stride = Kp
#define OFF_EW1   0          // 64 x 224 (K=200 zero-padded)
#define OFF_EW2   14336      // 64 x 64
#define OFF_WQ    18432      // unused by main (folded into M)
#define OFF_WK    22528      // unused by main
#define OFF_WV    26624
#define OFF_WO    30720
#define OFF_F1    34816
#define OFF_F2    38912
#define OFF_W1A   43008      // 64 x 128
#define OFF_W1B   51200      // 256 x 64
#define OFF_HB1W  67584      // 32 x 128
#define OFF_W2A   71680      // 64 x 128
#define OFF_W2B   79872      // 32 x 64
#define OFF_HB2W1 81920      // 32 x 128
#define WS_TOTAL  86016
#define OFF_M     86016      // 64 x 64 : M'[f][e] = (Wq Wk^T)[e][f] / 8
#define WS_TOTAL2 90112

__device__ __align__(16) __bf16 g_ws[WS_TOTAL2];
__device__ float g_v[64];    // v[d] = (Wk bq)[d] / 8

#define MFMA16(a,b,c) __builtin_amdgcn_mfma_f32_16x16x32_bf16(a,b,c,0,0,0)

// ---- LDS layout (bytes), per 1-wave block. Tail pad keeps all garbage
// A-fragment window over-reads (Sb needs +7168 B, ensB +4336 B) in-bounds.
#define L_H    0        // 18 rows x 72 bf16 (a: rows 0-8, b: rows 9-17)
#define L_W    2592     // work buffer, same shape
#define L_SB   5184     // states 2 x 224 bf16
#define L_ENS  6080     // ens 2 x 136 bf16
#define L_T1   6624     // t1 2 x 72 bf16
#define L_T2   6912     // t2 2 x 72 bf16
#define L_W1S  7200     // w1 2 x 256 bf16
#define L_ATT  8224     // att 2 x 81 f32
#define L_SNI  8872     // sNi 2 x 64 f32
#define L_VH   9384     // vh 18 f32 (+pad)
#define L_QV   9464     // qvals 16 f32
#define L_QNI  9528     // qni 16 f32
#define L_B1F  9592     // 2 x 32 f32
#define L_W2F  9848
#define L_T3F  10104    // ends 10360
#define L_TOTAL 12544   // incl. guard pad for over-reads

// ---------------- weight transform kernel ----------------
struct TP { const float* src[14]; };

__global__ __launch_bounds__(256) void wtrans(TP tp) {
    const int gid = blockIdx.x * 256 + threadIdx.x;
    if (gid >= WS_TOTAL) return;
    const int OFFS[14] = {OFF_EW1, OFF_EW2, OFF_WQ, OFF_WK, OFF_WV, OFF_WO, OFF_F1,
                          OFF_F2, OFF_W1A, OFF_W1B, OFF_HB1W, OFF_W2A, OFF_W2B, OFF_HB2W1};
    const int KPS[14]  = {224, 64, 64, 64, 64, 64, 64, 64, 128, 64, 128, 128, 64, 128};
    const int KRS[14]  = {200, 64, 64, 64, 64, 64, 64, 64, 128, 64, 128, 128, 64, 128};
    const int NS[14]   = {64, 64, 64, 64, 64, 64, 64, 64, 64, 256, 32, 64, 32, 32};
    int m = 0;
#pragma unroll
    for (int i = 1; i < 14; ++i) if (gid >= OFFS[i]) m = i;
    const int loc = gid - OFFS[m];
    const int Kp = KPS[m];
    const int n = loc / Kp;
    const int k = loc - n * Kp;
    float v = 0.f;
    if (k < KRS[m]) v = tp.src[m][(size_t)k * NS[m] + n];   // src is W[k][n]
    g_ws[gid] = (__bf16)v;
}

// ---------------- QK-fold precompute (parallel) ----------------
struct PP { const float *wq, *wk, *bq; };

__global__ __launch_bounds__(256) void wprep(PP pp) {
    const int b = blockIdx.x, t = threadIdx.x;
    if (b < 16) {
        const int idx = b * 256 + t;           // 4096 entries of M
        const int f = idx >> 6, e = idx & 63;
        float s = 0.f;
        for (int n = 0; n < 64; ++n) s += pp.wq[e * 64 + n] * pp.wk[f * 64 + n];
        g_ws[OFF_M + f * 64 + e] = (__bf16)(s * 0.125f);
    } else if (t < 64) {
        float s = 0.f;
        for (int n = 0; n < 64; ++n) s += pp.wk[t * 64 + n] * pp.bq[n];
        g_v[t] = s * 0.125f;
    }
}

// ---------------- main fused kernel ----------------
struct MainP {
    const float *qvals, *states, *hid, *eb1, *eb2, *bq, *bk, *bv, *bo,
        *l1g, *l1b, *fb1, *fb2, *l2g, *l2b, *niw, *nib, *ng, *nb,
        *b1a, *b1b, *hb1b, *b2a, *b2b, *hb2b1, *hw2, *hb2b2;
    float* out;
};

// tile projection A@WT+bias -> D (stores predicated i<9), barrier-free
template<bool RELU>
__device__ __forceinline__ void projT(const __bf16* A, const __bf16* WT, const float* bias,
                                      __bf16* D, int quad, int l15) {
    const bf16x8 a0 = *(const bf16x8*)(A + l15 * HPAD + quad * 8);
    const bf16x8 a1 = *(const bf16x8*)(A + l15 * HPAD + 32 + quad * 8);
    f32x4 acc[4] = {{0,0,0,0},{0,0,0,0},{0,0,0,0},{0,0,0,0}};
#pragma unroll
    for (int nt = 0; nt < 4; ++nt) {
        acc[nt] = MFMA16(a0, *(const bf16x8*)(WT + (size_t)(nt * 16 + l15) * 64 + quad * 8), acc[nt]);
        acc[nt] = MFMA16(a1, *(const bf16x8*)(WT + (size_t)(nt * 16 + l15) * 64 + 32 + quad * 8), acc[nt]);
    }
#pragma unroll
    for (int nt = 0; nt < 4; ++nt) {
        const float bv = bias[nt * 16 + l15];
#pragma unroll
        for (int r = 0; r < 4; ++r) {
            float val = acc[nt][r] + bv;
            if (RELU) val = fmaxf(val, 0.f);
            if (quad * 4 + r < 9) D[(quad * 4 + r) * HPAD + nt * 16 + l15] = (__bf16)val;
        }
    }
}

// projection + bias + residual + LayerNorm -> Hd (stores predicated i<9)
__device__ __forceinline__ void projLN(const __bf16* A, const __bf16* WT, const float* bias,
                                       const float* g, const float* bb, __bf16* Hd,
                                       int quad, int l15) {
    f32x4 acc[4] = {{0,0,0,0},{0,0,0,0},{0,0,0,0},{0,0,0,0}};
#pragma unroll
    for (int ks = 0; ks < 2; ++ks) {
        const int kk = ks * 32 + quad * 8;
        const bf16x8 af = *(const bf16x8*)(A + l15 * HPAD + kk);
#pragma unroll
        for (int nt = 0; nt < 4; ++nt)
            acc[nt] = MFMA16(af, *(const bf16x8*)(WT + (size_t)(nt * 16 + l15) * 64 + kk), acc[nt]);
    }
    float v[4][4], g4[4], b4[4];
#pragma unroll
    for (int nt = 0; nt < 4; ++nt) {
        const int col = nt * 16 + l15;
        const float bo = bias[col];
        g4[nt] = g[col]; b4[nt] = bb[col];
#pragma unroll
        for (int r = 0; r < 4; ++r)
            v[nt][r] = acc[nt][r] + bo + (float)Hd[(quad * 4 + r) * HPAD + col];
    }
#pragma unroll
    for (int r = 0; r < 4; ++r) {
        float s  = v[0][r] + v[1][r] + v[2][r] + v[3][r];
        float s2 = v[0][r]*v[0][r] + v[1][r]*v[1][r] + v[2][r]*v[2][r] + v[3][r]*v[3][r];
#pragma unroll
        for (int off = 1; off < 16; off <<= 1) {
            s  += __shfl_xor(s,  off, 64);
            s2 += __shfl_xor(s2, off, 64);
        }
        const float mu  = s * 0.015625f;
        const float var = s2 * 0.015625f - mu * mu;
        const float rs  = rsqrtf(var + 1e-5f);
#pragma unroll
        for (int nt = 0; nt < 4; ++nt)
            if (quad * 4 + r < 9)
                Hd[(quad * 4 + r) * HPAD + nt * 16 + l15] =
                    (__bf16)((v[nt][r] - mu) * rs * g4[nt] + b4[nt]);
    }
}

// One wave (64 threads) per block; block handles bt rows 2b, 2b+1.
// NO __syncthreads anywhere: all LDS deps are same-wave (in-order LDS pipe).
__global__ __launch_bounds__(64, 4) void mixer_main(MainP p) {
    extern __shared__ __align__(16) char smraw[];
    __bf16* H    = (__bf16*)(smraw + L_H);
    __bf16* W    = (__bf16*)(smraw + L_W);
    __bf16* Sb   = (__bf16*)(smraw + L_SB);
    __bf16* ensB = (__bf16*)(smraw + L_ENS);
    __bf16* T1   = (__bf16*)(smraw + L_T1);
    __bf16* T2   = (__bf16*)(smraw + L_T2);
    __bf16* w1S  = (__bf16*)(smraw + L_W1S);
    float* attU  = (float*)(smraw + L_ATT);
    float* sNi   = (float*)(smraw + L_SNI);
    float* vhS   = (float*)(smraw + L_VH);
    float* sQv   = (float*)(smraw + L_QV);
    float* qniL  = (float*)(smraw + L_QNI);
    float* B1f   = (float*)(smraw + L_B1F);
    float* W2f   = (float*)(smraw + L_W2F);
    float* T3f   = (float*)(smraw + L_T3F);

    const int bt0 = blockIdx.x * 2;
    const int lane = threadIdx.x;
    const int quad = lane >> 4, l15 = lane & 15;
    const __bf16* ws = g_ws;

    // ---- P0: stage hid -> H rows (x*9+n); states -> Sb (zero-padded); qvals ----
#pragma unroll
    for (int it = 0; it < 4; ++it) {
        const int u = it * 64 + lane;             // 256 float4 units = 2 x 512 floats
        const int x = u >> 7, rem = u & 127, n = rem >> 4, d4 = (rem & 15) * 4;
        const float4 v4 = *(const float4*)(p.hid + ((size_t)(bt0 + x) * 512 + n * 64 + d4));
        bf16x4 o; o[0] = (__bf16)v4.x; o[1] = (__bf16)v4.y; o[2] = (__bf16)v4.z; o[3] = (__bf16)v4.w;
        *(bf16x4*)(H + (x * 9 + n) * HPAD + d4) = o;
    }
#pragma unroll
    for (int it = 0; it < 2; ++it) {
        const int u = it * 64 + lane;             // 100 float4 units = 2 x 200 floats
        if (u < 100) {
            const int xr = u / 50, c4 = u - xr * 50;
            const float4 v4 = *(const float4*)(p.states + (size_t)(bt0 + xr) * 200 + c4 * 4);
            bf16x4 o; o[0] = (__bf16)v4.x; o[1] = (__bf16)v4.y; o[2] = (__bf16)v4.z; o[3] = (__bf16)v4.w;
            *(bf16x4*)(Sb + xr * 224 + c4 * 4) = o;
        }
    }
    if (lane < 48) { const int xr = lane / 24, c = lane - xr * 24; Sb[xr * 224 + 200 + c] = (__bf16)0.0f; }
    if (lane < 16) sQv[lane] = p.qvals[(size_t)bt0 * 8 + lane];

    // ---- P1: e = relu(states@EW1+b1); rows 0,1 valid; keep e in regs + W rows 0,1 ----
    float e_reg[4][4];
    {
        f32x4 acc[4] = {{0,0,0,0},{0,0,0,0},{0,0,0,0},{0,0,0,0}};
        for (int ks = 0; ks < 7; ++ks) {
            const int kk = ks * 32 + quad * 8;
            const bf16x8 af = *(const bf16x8*)(Sb + l15 * 224 + kk);
#pragma unroll
            for (int nt = 0; nt < 4; ++nt)
                acc[nt] = MFMA16(af, *(const bf16x8*)(ws + OFF_EW1 + (size_t)(nt * 16 + l15) * 224 + kk), acc[nt]);
        }
#pragma unroll
        for (int nt = 0; nt < 4; ++nt) {
            const float b1 = p.eb1[nt * 16 + l15];
#pragma unroll
            for (int r = 0; r < 4; ++r) {
                const float ev = fmaxf(acc[nt][r] + b1, 0.f);
                e_reg[nt][r] = ev;
                if (quad * 4 + r < 2) W[(quad * 4 + r) * HPAD + nt * 16 + l15] = (__bf16)ev;
            }
        }
    }

    // ---- P2: enc = tanh(e@EW2 + e + b2) -> H rows 8/17, ensB[:,0:64] ----
    {
        f32x4 acc[4] = {{0,0,0,0},{0,0,0,0},{0,0,0,0},{0,0,0,0}};
#pragma unroll
        for (int ks = 0; ks < 2; ++ks) {
            const int kk = ks * 32 + quad * 8;
            const bf16x8 af = *(const bf16x8*)(W + l15 * HPAD + kk);
#pragma unroll
            for (int nt = 0; nt < 4; ++nt)
                acc[nt] = MFMA16(af, *(const bf16x8*)(ws + OFF_EW2 + (size_t)(nt * 16 + l15) * 64 + kk), acc[nt]);
        }
#pragma unroll
        for (int nt = 0; nt < 4; ++nt) {
            const float b2 = p.eb2[nt * 16 + l15];
#pragma unroll
            for (int r = 0; r < 4; ++r) {
                const int xr = quad * 4 + r;
                if (xr < 2) {
                    const float ev = tanhf(acc[nt][r] + e_reg[nt][r] + b2);
                    H[(xr * 9 + 8) * HPAD + nt * 16 + l15] = (__bf16)ev;
                    ensB[xr * 136 + nt * 16 + l15] = (__bf16)ev;
                }
            }
        }
    }

    // ---- P3: G = h@M' -> W (pred i<9); vh = h.v ----
    for (int x = 0; x < 2; ++x) {
        const __bf16* A = H + x * 9 * HPAD;
        f32x4 acc[4] = {{0,0,0,0},{0,0,0,0},{0,0,0,0},{0,0,0,0}};
#pragma unroll
        for (int ks = 0; ks < 2; ++ks) {
            const int kk = ks * 32 + quad * 8;
            const bf16x8 af = *(const bf16x8*)(A + l15 * HPAD + kk);
#pragma unroll
            for (int nt = 0; nt < 4; ++nt)
                acc[nt] = MFMA16(af, *(const bf16x8*)(ws + OFF_M + (size_t)(nt * 16 + l15) * 64 + kk), acc[nt]);
        }
#pragma unroll
        for (int nt = 0; nt < 4; ++nt)
#pragma unroll
            for (int r = 0; r < 4; ++r)
                if (quad * 4 + r < 9)
                    W[(x * 9 + quad * 4 + r) * HPAD + nt * 16 + l15] = (__bf16)acc[nt][r];
    }
    if (lane < 18) {
        float s = 0.f;
#pragma unroll
        for (int c8 = 0; c8 < 8; ++c8) {
            const bf16x8 hv = *(const bf16x8*)(H + lane * HPAD + c8 * 8);
#pragma unroll
            for (int jj = 0; jj < 8; ++jj) s += (float)hv[jj] * g_v[c8 * 8 + jj];
        }
        vhS[lane] = s;
    }

    // ---- P45: S = G h^T + vh -> softmax -> attU; ah = att@h -> W (overwrite G) ----
    for (int x = 0; x < 2; ++x) {
        const int base = x * 9 * HPAD;
        f32x4 acc = {0, 0, 0, 0};
#pragma unroll
        for (int ks = 0; ks < 2; ++ks) {
            const int kk = ks * 32 + quad * 8;
            acc = MFMA16(*(const bf16x8*)(W + base + l15 * HPAD + kk),
                         *(const bf16x8*)(H + base + l15 * HPAD + kk), acc);
        }
        const float vh = (l15 < 9) ? vhS[x * 9 + l15] : 0.f;
#pragma unroll
        for (int r = 0; r < 4; ++r) {
            const int i = quad * 4 + r;
            float s = (l15 < 9) ? (acc[r] + vh) : -3.0e38f;
            float m = s;
#pragma unroll
            for (int off = 1; off < 16; off <<= 1) m = fmaxf(m, __shfl_xor(m, off, 64));
            float e = (l15 < 9) ? __expf(s - m) : 0.f;
            float sum = e;
#pragma unroll
            for (int off = 1; off < 16; off <<= 1) sum += __shfl_xor(sum, off, 64);
            if (i < 9 && l15 < 9) attU[x * 81 + i * 9 + l15] = e / sum;
        }
        float vreg[9];
#pragma unroll
        for (int jj = 0; jj < 9; ++jj) vreg[jj] = (float)H[base + jj * HPAD + lane];
#pragma unroll
        for (int i = 0; i < 9; ++i) {
            float a = 0.f;
#pragma unroll
            for (int jj = 0; jj < 9; ++jj) a += attU[x * 81 + i * 9 + jj] * vreg[jj];
            W[base + i * HPAD + lane] = (__bf16)a;
        }
    }

    // ---- P6: per x: attv -> LN1 -> FFN1 -> LN2 (all wave-local, no barriers) ----
    for (int x = 0; x < 2; ++x) {
        __bf16* Wb = W + x * 9 * HPAD;
        __bf16* Hb = H + x * 9 * HPAD;
        projT<false>(Wb, ws + OFF_WV, p.bv, Wb, quad, l15);                 // attv = ah@Wv+bv
        projLN(Wb, ws + OFF_WO, p.bo, p.l1g, p.l1b, Hb, quad, l15);         // h2
        projT<true>(Hb, ws + OFF_F1, p.fb1, Wb, quad, l15);                 // f = relu
        projLN(Wb, ws + OFF_F2, p.fb2, p.l2g, p.l2b, Hb, quad, l15);        // h3
    }

    // ---- ens second half = mean of h3 heads ----
    for (int x = 0; x < 2; ++x) {
        float s = 0.f;
#pragma unroll
        for (int i = 0; i < 8; ++i) s += (float)H[(x * 9 + i) * HPAD + lane];
        ensB[x * 136 + 64 + lane] = (__bf16)(s * 0.125f);
    }

    // ---- ni = sigmoid(LN7(h3@fc2ni + b)) ----
    {
        const int pr = lane >> 2, q4 = lane & 3;
        const int x = pr >> 3, n = pr & 7;
        float acc[7] = {0.f, 0.f, 0.f, 0.f, 0.f, 0.f, 0.f};
        const float* wni = p.niw + n * 448;
        for (int dd = 0; dd < 16; ++dd) {
            const int d = q4 * 16 + dd;
            const float hv = (float)H[(x * 9 + n) * HPAD + d];
#pragma unroll
            for (int e = 0; e < 7; ++e) acc[e] += hv * wni[d * 7 + e];
        }
#pragma unroll
        for (int e = 0; e < 7; ++e) {
            acc[e] += __shfl_xor(acc[e], 1, 64);
            acc[e] += __shfl_xor(acc[e], 2, 64);
        }
        if (q4 == 0) {
            float s = 0.f;
#pragma unroll
            for (int e = 0; e < 7; ++e) { acc[e] += p.nib[n * 7 + e]; s += acc[e]; }
            const float mu = s * (1.f / 7.f);
            float s2 = 0.f;
#pragma unroll
            for (int e = 0; e < 7; ++e) { const float d0 = acc[e] - mu; s2 += d0 * d0; }
            const float rs = rsqrtf(s2 * (1.f / 7.f) + 1e-5f);
#pragma unroll
            for (int e = 0; e < 7; ++e) {
                const float vv = (acc[e] - mu) * rs * p.ng[e] + p.nb[e];
                sNi[x * 64 + n * 8 + e] = 1.f / (1.f + __expf(-vv));
            }
        }
    }

    // ---- N_nn / eye outputs + q_ni ----
#pragma unroll
    for (int it = 0; it < 2; ++it) {
        const int id = it * 64 + lane;
        const int x = id >> 6, rem = id & 63, i = rem >> 3, jj = rem & 7;
        const float nf = (i == jj) ? 1.f : sNi[x * 64 + i * 8 + (jj - (jj > i ? 1 : 0))];
        p.out[NN_OFF + (size_t)(bt0 + x) * 64 + rem] = nf;
        p.out[EYE_OFF + (size_t)(bt0 + x) * 64 + rem] = (i == jj) ? 1.f : 0.f;
    }
    {
        const int pr = lane >> 2, q4 = lane & 3;
        const int x = pr >> 3, i = pr & 7;
        float s = 0.f;
#pragma unroll
        for (int jo = 0; jo < 2; ++jo) {
            const int j = q4 * 2 + jo;
            const float nf = (j == i) ? 1.f : sNi[x * 64 + i * 8 + (j - (j > i ? 1 : 0))];
            s += sQv[x * 8 + j] * nf;
        }
        s += __shfl_xor(s, 1, 64);
        s += __shfl_xor(s, 2, 64);
        if (q4 == 0) qniL[x * 8 + i] = s;
    }

    // ---- hyper stage 1: t1 = relu(ens@W1A+b1a) -> T1; t2 -> T2 ----
#pragma unroll
    for (int m2 = 0; m2 < 2; ++m2) {
        const __bf16* wt = ws + (m2 == 0 ? OFF_W1A : OFF_W2A);
        const float* bias = m2 == 0 ? p.b1a : p.b2a;
        __bf16* dst = m2 == 0 ? T1 : T2;
        f32x4 acc[4] = {{0,0,0,0},{0,0,0,0},{0,0,0,0},{0,0,0,0}};
#pragma unroll
        for (int ks = 0; ks < 4; ++ks) {
            const int kk = ks * 32 + quad * 8;
            const bf16x8 af = *(const bf16x8*)(ensB + l15 * 136 + kk);
#pragma unroll
            for (int nt = 0; nt < 4; ++nt)
                acc[nt] = MFMA16(af, *(const bf16x8*)(wt + (size_t)(nt * 16 + l15) * 128 + kk), acc[nt]);
        }
#pragma unroll
        for (int nt = 0; nt < 4; ++nt) {
            const float bb = bias[nt * 16 + l15];
#pragma unroll
            for (int r = 0; r < 4; ++r)
                if (quad * 4 + r < 2)
                    dst[(quad * 4 + r) * HPAD + nt * 16 + l15] = (__bf16)fmaxf(acc[nt][r] + bb, 0.f);
        }
    }

    // ---- hyper stage 2: w1 (16 nt), b1 (2), w2 (2), t3 (2) ----
    for (int nt16 = 0; nt16 < 16; ++nt16) {
        f32x4 acc = {0, 0, 0, 0};
#pragma unroll
        for (int ks = 0; ks < 2; ++ks) {
            const int kk = ks * 32 + quad * 8;
            acc = MFMA16(*(const bf16x8*)(T1 + l15 * HPAD + kk),
                         *(const bf16x8*)(ws + OFF_W1B + (size_t)(nt16 * 16 + l15) * 64 + kk), acc);
        }
        const float bb = p.b1b[nt16 * 16 + l15];
#pragma unroll
        for (int r = 0; r < 4; ++r)
            if (quad * 4 + r < 2)
                w1S[(quad * 4 + r) * 256 + nt16 * 16 + l15] = (__bf16)fabsf(acc[r] + bb);
    }
#pragma unroll
    for (int nt = 0; nt < 2; ++nt) {
        f32x4 accB = {0,0,0,0}, accT = {0,0,0,0}, accW = {0,0,0,0};
#pragma unroll
        for (int ks = 0; ks < 4; ++ks) {
            const int kk = ks * 32 + quad * 8;
            const bf16x8 af = *(const bf16x8*)(ensB + l15 * 136 + kk);
            accB = MFMA16(af, *(const bf16x8*)(ws + OFF_HB1W  + (size_t)(nt * 16 + l15) * 128 + kk), accB);
            accT = MFMA16(af, *(const bf16x8*)(ws + OFF_HB2W1 + (size_t)(nt * 16 + l15) * 128 + kk), accT);
        }
#pragma unroll
        for (int ks = 0; ks < 2; ++ks) {
            const int kk = ks * 32 + quad * 8;
            accW = MFMA16(*(const bf16x8*)(T2 + l15 * HPAD + kk),
                          *(const bf16x8*)(ws + OFF_W2B + (size_t)(nt * 16 + l15) * 64 + kk), accW);
        }
        const float bB = p.hb1b[nt * 16 + l15];
        const float bT = p.hb2b1[nt * 16 + l15];
        const float bW = p.b2b[nt * 16 + l15];
#pragma unroll
        for (int r = 0; r < 4; ++r) {
            const int xr = quad * 4 + r;
            if (xr < 2) {
                B1f[xr * 32 + nt * 16 + l15] = accB[r] + bB;
                T3f[xr * 32 + nt * 16 + l15] = fmaxf(accT[r] + bT, 0.f);
                W2f[xr * 32 + nt * 16 + l15] = fabsf(accW[r] + bW);
            }
        }
    }

    // ---- P11: hidden = elu(q_ni@w1 + b1); y = hidden@w2 + t3.hw2 + b2 ----
    {
        const int x = lane >> 5, sub = lane & 31;
        float a = B1f[x * 32 + sub];
#pragma unroll
        for (int i = 0; i < 8; ++i) a += qniL[x * 8 + i] * (float)w1S[x * 256 + i * 32 + sub];
        const float hid = a > 0.f ? a : (__expf(a) - 1.f);
        float red = hid * W2f[x * 32 + sub] + T3f[x * 32 + sub] * p.hw2[sub];
#pragma unroll
        for (int off = 1; off < 32; off <<= 1) red += __shfl_xor(red, off, 64);
        if (sub == 0) p.out[bt0 + x] = red + p.hb2b2[0];
    }
}

extern "C" void kernel_launch(void* const* d_in, const int* in_sizes, int n_in,
                              void* d_out, int out_size, void* d_ws, size_t ws_size,
                              hipStream_t stream) {
    TP tp;
    tp.src[0]  = (const float*)d_in[3];   // enc_w1
    tp.src[1]  = (const float*)d_in[5];   // enc_w2
    tp.src[2]  = (const float*)d_in[7];   // wq
    tp.src[3]  = (const float*)d_in[9];   // wk
    tp.src[4]  = (const float*)d_in[11];  // wv
    tp.src[5]  = (const float*)d_in[13];  // wo
    tp.src[6]  = (const float*)d_in[17];  // ffn_w1
    tp.src[7]  = (const float*)d_in[19];  // ffn_w2
    tp.src[8]  = (const float*)d_in[27];  // w1a
    tp.src[9]  = (const float*)d_in[29];  // w1b
    tp.src[10] = (const float*)d_in[31];  // hb1w
    tp.src[11] = (const float*)d_in[33];  // w2a
    tp.src[12] = (const float*)d_in[35];  // w2b
    tp.src[13] = (const float*)d_in[37];  // hb2w1
    wtrans<<<(WS_TOTAL + 255) / 256, 256, 0, stream>>>(tp);

    PP pqk;
    pqk.wq = (const float*)d_in[7];
    pqk.wk = (const float*)d_in[9];
    pqk.bq = (const float*)d_in[8];
    wprep<<<17, 256, 0, stream>>>(pqk);

    MainP p;
    p.qvals = (const float*)d_in[0];
    p.states = (const float*)d_in[1];
    p.hid = (const float*)d_in[2];
    p.eb1 = (const float*)d_in[4];
    p.eb2 = (const float*)d_in[6];
    p.bq = (const float*)d_in[8];
    p.bk = (const float*)d_in[10];
    p.bv = (const float*)d_in[12];
    p.bo = (const float*)d_in[14];
    p.l1g = (const float*)d_in[15];
    p.l1b = (const float*)d_in[16];
    p.fb1 = (const float*)d_in[18];
    p.fb2 = (const float*)d_in[20];
    p.l2g = (const float*)d_in[21];
    p.l2b = (const float*)d_in[22];
    p.niw = (const float*)d_in[23];
    p.nib = (const float*)d_in[24];
    p.ng = (const float*)d_in[25];
    p.nb = (const float*)d_in[26];
    p.b1a = (const float*)d_in[28];
    p.b1b = (const float*)d_in[30];
    p.hb1b = (const float*)d_in[32];
    p.b2a = (const float*)d_in[34];
    p.b2b = (const float*)d_in[36];
    p.hb2b1 = (const float*)d_in[38];
    p.hw2 = (const float*)d_in[39];
    p.hb2b2 = (const float*)d_in[40];
    p.out = (float*)d_out;

    mixer_main<<<ROWSG / 2, 64, L_TOTAL, stream>>>(p);
}